// Round 1
// baseline (130.478 us; speedup 1.0000x reference)
//
#include <hip/hip_runtime.h>

typedef __attribute__((ext_vector_type(8))) short short8;
typedef __attribute__((ext_vector_type(8))) unsigned short ushort8;
typedef __attribute__((ext_vector_type(4))) float f32x4;
typedef unsigned int u32;
typedef unsigned short u16;

#define AS_GLOBAL(p) ((const __attribute__((address_space(1))) u32*)(p))
#define AS_LDS(p) ((__attribute__((address_space(3))) u32*)(p))

#define NB 8192
#define ND 512
#define NH 128

// workspace byte offsets (total 15,352,320 bytes)
#define OFF_XBF    0u          // [8192][512] bf16
#define OFF_W1PT   8388608u    // [32][128][512] bf16  (W1' transposed, BN folded)
#define OFF_W2T    12582912u   // [32][64][128] bf16   (eW2 transposed)
#define OFF_RW1PT  13107200u   // [2][64][512] bf16
#define OFF_B1P    13238272u   // [32][128] f32
#define OFF_RB1P   13254656u   // [2][64] f32
#define OFF_RW     13255168u   // [2][8192][16] f32  router weights
#define OFF_S      14303744u   // [32][8192] f32     expert sigmoid outputs

__device__ __forceinline__ u16 f2bf(float f) {
  union { float f; u32 u; } v; v.f = f;
  return (u16)((v.u + 0x7FFFu + ((v.u >> 16) & 1u)) >> 16);
}

// ---------------- K0: x -> bf16 ----------------
__global__ void k_cvt_x(const float* __restrict__ x, u16* __restrict__ xbf) {
  int i = (blockIdx.x * 256 + threadIdx.x) * 8;
  const float4* p = (const float4*)(x + i);
  float4 v0 = p[0], v1 = p[1];
  ushort8 r;
  r[0] = f2bf(v0.x); r[1] = f2bf(v0.y); r[2] = f2bf(v0.z); r[3] = f2bf(v0.w);
  r[4] = f2bf(v1.x); r[5] = f2bf(v1.y); r[6] = f2bf(v1.z); r[7] = f2bf(v1.w);
  *(ushort8*)(xbf + i) = r;
}

// ---------------- K1: fold BN into W1, transpose weights, bf16 ----------------
__global__ void k_prep(
    const float* __restrict__ ebn_g, const float* __restrict__ ebn_b,
    const float* __restrict__ ebn_m, const float* __restrict__ ebn_v,
    const float* __restrict__ eW1, const float* __restrict__ eb1,
    const float* __restrict__ eW2,
    const float* __restrict__ rbn_g, const float* __restrict__ rbn_b,
    const float* __restrict__ rbn_m, const float* __restrict__ rbn_v,
    const float* __restrict__ rW1, const float* __restrict__ rb1,
    u16* __restrict__ w1pt, float* __restrict__ b1p,
    u16* __restrict__ w2t, u16* __restrict__ rw1pt, float* __restrict__ rb1p)
{
  int blk = blockIdx.x, t = threadIdx.x;
  if (blk < 32) {
    int pair = blk;                        // c*16+e
    int h = t >> 1, half = t & 1;
    const float* g  = ebn_g + pair * ND;
    const float* b  = ebn_b + pair * ND;
    const float* m  = ebn_m + pair * ND;
    const float* vv = ebn_v + pair * ND;
    const float* w1 = eW1 + (size_t)pair * ND * NH;
    float acc = 0.f;
    for (int d = half * 256; d < half * 256 + 256; ++d) {
      float a  = g[d] * rsqrtf(vv[d] + 1e-5f);
      float cc = b[d] - m[d] * a;
      float w  = w1[d * NH + h];
      w1pt[((u32)pair * NH + h) * ND + d] = f2bf(a * w);
      acc += cc * w;
    }
    float tot = acc + __shfl_xor(acc, 1, 64);
    if (half == 0) b1p[pair * NH + h] = eb1[pair * NH + h] + tot;
    // W2 transpose -> [n=64][k=128] bf16
    const float* w2 = eW2 + (size_t)pair * NH * 64;
    int n = t & 63, kk = t >> 6;
    for (int k = kk * 32; k < kk * 32 + 32; ++k)
      w2t[((u32)pair * 64 + n) * NH + k] = f2bf(w2[k * 64 + n]);
  } else {
    int c = blk - 32;
    int n = t >> 2, q = t & 3;
    const float* g  = rbn_g + c * ND;
    const float* b  = rbn_b + c * ND;
    const float* m  = rbn_m + c * ND;
    const float* vv = rbn_v + c * ND;
    const float* w1 = rW1 + (size_t)c * ND * 64;
    float acc = 0.f;
    for (int d = q * 128; d < q * 128 + 128; ++d) {
      float a  = g[d] * rsqrtf(vv[d] + 1e-5f);
      float cc = b[d] - m[d] * a;
      float w  = w1[d * 64 + n];
      rw1pt[((u32)c * 64 + n) * ND + d] = f2bf(a * w);
      acc += cc * w;
    }
    acc += __shfl_xor(acc, 1, 64);
    acc += __shfl_xor(acc, 2, 64);
    if (q == 0) rb1p[c * 64 + n] = rb1[c * 64 + n] + acc;
  }
}

// ---------------- K2: router ----------------
// grid 256 = 2 branches x 128 tiles of 64 rows; 4 waves, each 16 rows x 64 cols MFMA
__global__ __launch_bounds__(256) void k_router(
    const u16* __restrict__ xbf, const u16* __restrict__ rw1pt,
    const float* __restrict__ rb1p, const float* __restrict__ rW2,
    const float* __restrict__ rb2, const float* __restrict__ rW3,
    const float* __restrict__ rb3, float* __restrict__ rwbuf)
{
  __shared__ float h1l[64][65];
  const int tid = threadIdx.x;
  const int lane = tid & 63;
  const int wv = tid >> 6;
  const int q = lane >> 4;
  const int lr = lane & 15;
  const int c = blockIdx.x >> 7;
  const int r0 = (blockIdx.x & 127) * 64;

  f32x4 acc[4] = {};
  const u16* xrow  = xbf + (((u32)r0 + wv * 16 + lr) << 9);
  const u16* wbase = rw1pt + ((u32)c * 64 << 9);
  for (int kb = 0; kb < 16; ++kb) {
    short8 a = *(const short8*)(xrow + kb * 32 + q * 8);
#pragma unroll
    for (int u = 0; u < 4; ++u) {
      short8 b = *(const short8*)(wbase + (((u32)(u * 16 + lr)) << 9) + kb * 32 + q * 8);
      acc[u] = __builtin_amdgcn_mfma_f32_16x16x32_bf16(a, b, acc[u], 0, 0, 0);
    }
  }
#pragma unroll
  for (int u = 0; u < 4; ++u) {
    int n = u * 16 + lr;
    float bias = rb1p[c * 64 + n];
#pragma unroll
    for (int i = 0; i < 4; ++i) {
      float v = acc[u][i] + bias;
      h1l[wv * 16 + q * 4 + i][n] = v > 0.f ? v : 0.f;
    }
  }
  __syncthreads();
  if (tid < 64) {
    int row = tid;
    float h2[32];
    const float* W2 = rW2 + c * 64 * 32;
    const float* B2 = rb2 + c * 32;
#pragma unroll
    for (int n = 0; n < 32; ++n) {
      float a2 = B2[n];
      for (int k = 0; k < 64; ++k) a2 += h1l[row][k] * W2[k * 32 + n];
      h2[n] = a2 > 0.f ? a2 : 0.f;
    }
    const float* W3 = rW3 + c * 32 * 16;
    const float* B3 = rb3 + c * 16;
    float lg[16]; float mx = -1e30f;
#pragma unroll
    for (int e = 0; e < 16; ++e) {
      float a3 = B3[e];
#pragma unroll
      for (int k = 0; k < 32; ++k) a3 += h2[k] * W3[k * 16 + e];
      lg[e] = a3; mx = mx > a3 ? mx : a3;
    }
    float sm = 0.f;
#pragma unroll
    for (int e = 0; e < 16; ++e) { lg[e] = __expf(lg[e] - mx); sm += lg[e]; }
    float inv = 1.f / sm;
    float* dst = rwbuf + ((u32)c * NB + r0 + row) * 16;
#pragma unroll
    for (int e = 0; e < 16; ++e) dst[e] = lg[e] * inv;
  }
}

// ---------------- K3: experts ----------------
// grid 2048 = 64 btiles (major) x 32 pairs (minor, L2-shares x across pairs)
// block: 256 thr, 128 rows x 128 cols, BK=32 double-buffered global_load_lds
__global__ __launch_bounds__(256, 2) void k_expert(
    const u16* __restrict__ xbf, const u16* __restrict__ w1pt,
    const float* __restrict__ b1p, const u16* __restrict__ w2t,
    const float* __restrict__ eb2, const float* __restrict__ eW3,
    const float* __restrict__ eb3, float* __restrict__ sbuf)
{
  __shared__ __align__(16) unsigned char smem[32768];
  const int tid = threadIdx.x;
  const int lane = tid & 63;
  const int wv = tid >> 6;
  const int q = lane >> 4;
  const int lr = lane & 15;
  const int pair = blockIdx.x & 31;
  const int bt = blockIdx.x >> 5;
  const int r0 = bt * 128;
  const int wr = wv >> 1, wc = wv & 1;

  f32x4 acc[4][4] = {};

  // staging: per buf: xs[128][32]bf16 @0, ws[128][32]bf16 @8192.
  // 16B slot (row,kq) stored at slot row*4 + (kq ^ ((row>>1)&3))  (inverse == same map)
  auto stage = [&](int buf, int kb) {
#pragma unroll
    for (int i = 0; i < 2; ++i) {
      int s = ((wv * 2048 + i * 1024) >> 4) + lane;
      int row = s >> 2;
      int kq = (s & 3) ^ ((row >> 1) & 3);
      const u16* src = xbf + (((u32)(r0 + row)) << 9) + kb * 32 + kq * 8;
      __builtin_amdgcn_global_load_lds(AS_GLOBAL(src),
          AS_LDS(smem + buf * 16384 + wv * 2048 + i * 1024), 16, 0, 0);
    }
#pragma unroll
    for (int i = 0; i < 2; ++i) {
      int s = ((wv * 2048 + i * 1024) >> 4) + lane;
      int n = s >> 2;
      int kq = (s & 3) ^ ((n >> 1) & 3);
      const u16* src = w1pt + (((u32)pair * 128 + n) << 9) + kb * 32 + kq * 8;
      __builtin_amdgcn_global_load_lds(AS_GLOBAL(src),
          AS_LDS(smem + buf * 16384 + 8192 + wv * 2048 + i * 1024), 16, 0, 0);
    }
  };

  stage(0, 0);
  __syncthreads();
  int buf = 0;
  for (int kb = 0; kb < 16; ++kb) {
    if (kb < 15) stage(buf ^ 1, kb + 1);
    short8 a[4], b[4];
#pragma unroll
    for (int t = 0; t < 4; ++t) {
      int row = wr * 64 + t * 16 + lr;
      int slot = row * 4 + (q ^ ((row >> 1) & 3));
      a[t] = *(const short8*)(smem + buf * 16384 + slot * 16);
    }
#pragma unroll
    for (int u = 0; u < 4; ++u) {
      int n = wc * 64 + u * 16 + lr;
      int slot = n * 4 + (q ^ ((n >> 1) & 3));
      b[u] = *(const short8*)(smem + buf * 16384 + 8192 + slot * 16);
    }
#pragma unroll
    for (int t = 0; t < 4; ++t)
#pragma unroll
      for (int u = 0; u < 4; ++u)
        acc[t][u] = __builtin_amdgcn_mfma_f32_16x16x32_bf16(a[t], b[u], acc[t][u], 0, 0, 0);
    __syncthreads();
    buf ^= 1;
  }

  // h1 = relu(acc + b1') -> bf16 in smem[0..32K), row-major [128][128], XOR-swizzled
  {
    const float* b1 = b1p + pair * NH;
    float bias[4];
#pragma unroll
    for (int u = 0; u < 4; ++u) bias[u] = b1[wc * 64 + u * 16 + lr];
#pragma unroll
    for (int t = 0; t < 4; ++t)
#pragma unroll
      for (int u = 0; u < 4; ++u) {
        int n = wc * 64 + u * 16 + lr;
#pragma unroll
        for (int i = 0; i < 4; ++i) {
          int row = wr * 64 + t * 16 + q * 4 + i;
          float v = acc[t][u][i] + bias[u];
          v = v > 0.f ? v : 0.f;
          int byteoff = (row * 256 + n * 2) ^ ((row & 7) << 4);
          *(u16*)(smem + byteoff) = f2bf(v);
        }
      }
  }
  __syncthreads();

  // GEMM2: h2[128x64] = h1[128x128] @ W2T; wave wv owns rows wv*32..+31
  f32x4 acc2[2][4] = {};
  const u16* w2 = w2t + (u32)pair * 64 * NH;
#pragma unroll
  for (int kb2 = 0; kb2 < 4; ++kb2) {
    short8 a2[2], bb[4];
#pragma unroll
    for (int t2 = 0; t2 < 2; ++t2) {
      int row = wv * 32 + t2 * 16 + lr;
      int byteoff = (row * 256 + kb2 * 64 + q * 16) ^ ((row & 7) << 4);
      a2[t2] = *(const short8*)(smem + byteoff);
    }
#pragma unroll
    for (int u2 = 0; u2 < 4; ++u2) {
      int n = u2 * 16 + lr;
      bb[u2] = *(const short8*)(w2 + n * NH + kb2 * 32 + q * 8);
    }
#pragma unroll
    for (int t2 = 0; t2 < 2; ++t2)
#pragma unroll
      for (int u2 = 0; u2 < 4; ++u2)
        acc2[t2][u2] = __builtin_amdgcn_mfma_f32_16x16x32_bf16(a2[t2], bb[u2], acc2[t2][u2], 0, 0, 0);
  }

  // epilogue: s = sigmoid(relu(h2 + b2) . W3 + b3)
  {
    const float* b2 = eb2 + pair * 64;
    const float* w3 = eW3 + pair * 64;
    float b3 = eb3[pair];
    float bb2[4], bw3[4];
#pragma unroll
    for (int u2 = 0; u2 < 4; ++u2) {
      int n = u2 * 16 + lr;
      bb2[u2] = b2[n];
      bw3[u2] = w3[n];
    }
#pragma unroll
    for (int t2 = 0; t2 < 2; ++t2) {
      float p[4] = {0.f, 0.f, 0.f, 0.f};
#pragma unroll
      for (int u2 = 0; u2 < 4; ++u2)
#pragma unroll
        for (int i = 0; i < 4; ++i) {
          float h = acc2[t2][u2][i] + bb2[u2];
          h = h > 0.f ? h : 0.f;
          p[i] += h * bw3[u2];
        }
#pragma unroll
      for (int m = 1; m < 16; m <<= 1)
#pragma unroll
        for (int i = 0; i < 4; ++i) p[i] += __shfl_xor(p[i], m, 64);
      if (lr == 0) {
#pragma unroll
        for (int i = 0; i < 4; ++i) {
          int row = wv * 32 + t2 * 16 + q * 4 + i;
          float z = p[i] + b3;
          sbuf[(u32)pair * NB + r0 + row] = 1.f / (1.f + __expf(-z));
        }
      }
    }
  }
}

// ---------------- K4: combine ----------------
__global__ void k_combine(const float* __restrict__ rwbuf, const float* __restrict__ sbuf,
                          const float* __restrict__ bw, float* __restrict__ out)
{
  int b = blockIdx.x * 256 + threadIdx.x;
  float total = 0.f;
#pragma unroll
  for (int c = 0; c < 2; ++c) {
    const float* rwp = rwbuf + ((u32)c * NB + b) * 16;
    float acc = 0.f;
#pragma unroll
    for (int e = 0; e < 16; ++e)
      acc += rwp[e] * sbuf[((u32)(c * 16 + e)) * NB + b];
    total += bw[c] * acc;
  }
  out[b] = total;
}

extern "C" void kernel_launch(void* const* d_in, const int* in_sizes, int n_in,
                              void* d_out, int out_size, void* d_ws, size_t ws_size,
                              hipStream_t stream) {
  const float* x     = (const float*)d_in[0];
  const float* rbn_g = (const float*)d_in[1];
  const float* rbn_b = (const float*)d_in[2];
  const float* rbn_m = (const float*)d_in[3];
  const float* rbn_v = (const float*)d_in[4];
  const float* rW1   = (const float*)d_in[5];
  const float* rb1   = (const float*)d_in[6];
  const float* rW2   = (const float*)d_in[7];
  const float* rb2   = (const float*)d_in[8];
  const float* rW3   = (const float*)d_in[9];
  const float* rb3   = (const float*)d_in[10];
  const float* ebn_g = (const float*)d_in[11];
  const float* ebn_b = (const float*)d_in[12];
  const float* ebn_m = (const float*)d_in[13];
  const float* ebn_v = (const float*)d_in[14];
  const float* eW1   = (const float*)d_in[15];
  const float* eb1   = (const float*)d_in[16];
  const float* eW2   = (const float*)d_in[17];
  const float* eb2   = (const float*)d_in[18];
  const float* eW3   = (const float*)d_in[19];
  const float* eb3   = (const float*)d_in[20];
  const float* bw    = (const float*)d_in[21];

  char* ws = (char*)d_ws;
  u16*   xbf   = (u16*)(ws + OFF_XBF);
  u16*   w1pt  = (u16*)(ws + OFF_W1PT);
  u16*   w2t   = (u16*)(ws + OFF_W2T);
  u16*   rw1pt = (u16*)(ws + OFF_RW1PT);
  float* b1p   = (float*)(ws + OFF_B1P);
  float* rb1p  = (float*)(ws + OFF_RB1P);
  float* rwbuf = (float*)(ws + OFF_RW);
  float* sbuf  = (float*)(ws + OFF_S);

  k_cvt_x<<<dim3(NB * ND / 8 / 256), dim3(256), 0, stream>>>(x, xbf);
  k_prep<<<dim3(34), dim3(256), 0, stream>>>(
      ebn_g, ebn_b, ebn_m, ebn_v, eW1, eb1, eW2,
      rbn_g, rbn_b, rbn_m, rbn_v, rW1, rb1,
      w1pt, b1p, w2t, rw1pt, rb1p);
  k_router<<<dim3(256), dim3(256), 0, stream>>>(
      xbf, rw1pt, rb1p, rW2, rb2, rW3, rb3, rwbuf);
  k_expert<<<dim3(2048), dim3(256), 0, stream>>>(
      xbf, w1pt, b1p, w2t, eb2, eW3, eb3, sbuf);
  k_combine<<<dim3(NB / 256), dim3(256), 0, stream>>>(rwbuf, sbuf, bw, (float*)d_out);
}

// Round 2
// 103.855 us; speedup vs baseline: 1.2564x; 1.2564x over previous
//
#include <hip/hip_runtime.h>

typedef __attribute__((ext_vector_type(8))) short short8;
typedef __attribute__((ext_vector_type(8))) unsigned short ushort8;
typedef __attribute__((ext_vector_type(4))) float f32x4;
typedef unsigned int u32;
typedef unsigned short u16;

#define AS_GLOBAL(p) ((const __attribute__((address_space(1))) u32*)(p))
#define AS_LDS(p) ((__attribute__((address_space(3))) u32*)(p))

#define NB 8192
#define ND 512
#define NH 128

// workspace byte offsets (total 15,352,320 bytes)
#define OFF_XBF    0u          // [8192][512] bf16
#define OFF_W1PT   8388608u    // [32][128][512] bf16  (W1' transposed, BN folded)
#define OFF_W2T    12582912u   // [32][64][128] bf16   (eW2 transposed)
#define OFF_RW1PT  13107200u   // [2][64][512] bf16
#define OFF_B1P    13238272u   // [32][128] f32
#define OFF_RB1P   13254656u   // [2][64] f32
#define OFF_RW     13255168u   // [2][8192][16] f32  router weights (pbias aliases this early)
#define OFF_S      14303744u   // [32][8192] f32     expert sigmoid outputs

__device__ __forceinline__ u16 f2bf(float f) {
  union { float f; u32 u; } v; v.f = f;
  return (u16)((v.u + 0x7FFFu + ((v.u >> 16) & 1u)) >> 16);
}

// ---------------- K0: x -> bf16 ----------------
__global__ void k_cvt_x(const float* __restrict__ x, u16* __restrict__ xbf) {
  int i = (blockIdx.x * 256 + threadIdx.x) * 8;
  const float4* p = (const float4*)(x + i);
  float4 v0 = p[0], v1 = p[1];
  ushort8 r;
  r[0] = f2bf(v0.x); r[1] = f2bf(v0.y); r[2] = f2bf(v0.z); r[3] = f2bf(v0.w);
  r[4] = f2bf(v1.x); r[5] = f2bf(v1.y); r[6] = f2bf(v1.z); r[7] = f2bf(v1.w);
  *(ushort8*)(xbf + i) = r;
}

// ---------------- K1a: fold BN into W1 (coalesced LDS transpose) ----------------
// grid 256 = 32 pairs x 8 d-chunks of 64; partial bias -> pbias[pair][chunk][128]
__global__ __launch_bounds__(256) void k_prep_w1(
    const float* __restrict__ eg, const float* __restrict__ ebb,
    const float* __restrict__ em, const float* __restrict__ ev,
    const float* __restrict__ eW1, u16* __restrict__ w1pt,
    float* __restrict__ pbias)
{
  __shared__ float sa[64], sc[64];
  __shared__ u16 tile[64][128];
  __shared__ float pb2[2][128];
  const int pair = blockIdx.x >> 3, dc = blockIdx.x & 7;
  const int d0 = dc * 64;
  const int t = threadIdx.x;
  if (t < 64) {
    int d = pair * ND + d0 + t;
    float a = eg[d] * rsqrtf(ev[d] + 1e-5f);
    sa[t] = a;
    sc[t] = ebb[d] - em[d] * a;
  }
  __syncthreads();
  const int h = t & 127, pr = t >> 7;
  float acc = 0.f;
  const float* src = eW1 + (size_t)pair * ND * NH + (size_t)d0 * NH;
#pragma unroll
  for (int i = 0; i < 32; ++i) {
    int dl = i * 2 + pr;
    float w = src[dl * NH + h];
    tile[dl][h] = f2bf(w * sa[dl]);
    acc += w * sc[dl];
  }
  pb2[pr][h] = acc;
  __syncthreads();
  {
    int hh = t >> 1, half = t & 1;
    u16* dst = w1pt + ((u32)(pair * NH + hh)) * ND + d0 + half * 32;
#pragma unroll
    for (int v8 = 0; v8 < 4; ++v8) {
      ushort8 r;
#pragma unroll
      for (int j = 0; j < 8; ++j) r[j] = tile[half * 32 + v8 * 8 + j][hh];
      *(ushort8*)(dst + v8 * 8) = r;
    }
  }
  if (t < 128) pbias[(u32)(pair * 8 + dc) * 128 + t] = pb2[0][t] + pb2[1][t];
}

// ---------------- K1b: bias reduce + W2 transpose + router fold ----------------
__global__ void k_prep_rest(
    const float* __restrict__ pbias, const float* __restrict__ eb1,
    const float* __restrict__ eW2,
    const float* __restrict__ rbn_g, const float* __restrict__ rbn_b,
    const float* __restrict__ rbn_m, const float* __restrict__ rbn_v,
    const float* __restrict__ rW1, const float* __restrict__ rb1,
    float* __restrict__ b1p, u16* __restrict__ w2t,
    u16* __restrict__ rw1pt, float* __restrict__ rb1p)
{
  int blk = blockIdx.x, t = threadIdx.x;
  if (blk < 32) {
    int pair = blk;
    if (t < 128) {
      float s = eb1[pair * NH + t];
#pragma unroll
      for (int dc = 0; dc < 8; ++dc) s += pbias[(u32)(pair * 8 + dc) * 128 + t];
      b1p[pair * NH + t] = s;
    }
    const float* w2 = eW2 + (size_t)pair * NH * 64;
    int n = t & 63, kk = t >> 6;
    for (int k = kk * 32; k < kk * 32 + 32; ++k)
      w2t[((u32)pair * 64 + n) * NH + k] = f2bf(w2[k * 64 + n]);
  } else {
    int c = blk - 32;
    int n = t >> 2, q = t & 3;
    const float* g  = rbn_g + c * ND;
    const float* b  = rbn_b + c * ND;
    const float* m  = rbn_m + c * ND;
    const float* vv = rbn_v + c * ND;
    const float* w1 = rW1 + (size_t)c * ND * 64;
    float acc = 0.f;
    for (int d = q * 128; d < q * 128 + 128; ++d) {
      float a  = g[d] * rsqrtf(vv[d] + 1e-5f);
      float cc = b[d] - m[d] * a;
      float w  = w1[d * 64 + n];
      rw1pt[((u32)c * 64 + n) * ND + d] = f2bf(a * w);
      acc += cc * w;
    }
    acc += __shfl_xor(acc, 1, 64);
    acc += __shfl_xor(acc, 2, 64);
    if (q == 0) rb1p[c * 64 + n] = rb1[c * 64 + n] + acc;
  }
}

// ---------------- K2: router ----------------
// grid 256 = 2 branches x 128 tiles of 64 rows; 4 waves MFMA + parallel tail
__global__ __launch_bounds__(256) void k_router(
    const u16* __restrict__ xbf, const u16* __restrict__ rw1pt,
    const float* __restrict__ rb1p, const float* __restrict__ rW2,
    const float* __restrict__ rb2, const float* __restrict__ rW3,
    const float* __restrict__ rb3, float* __restrict__ rwbuf)
{
  __shared__ float h1l[64][65];
  __shared__ float h2l[64][33];
  __shared__ float w2s[2048];
  __shared__ float w3s[512];
  const int tid = threadIdx.x;
  const int lane = tid & 63;
  const int wv = tid >> 6;
  const int q = lane >> 4;
  const int lr = lane & 15;
  const int c = blockIdx.x >> 7;
  const int r0 = (blockIdx.x & 127) * 64;

  // stage W2/W3 to LDS (covered by the first __syncthreads below)
  {
    const float* W2 = rW2 + c * 2048;
    *(float4*)(w2s + tid * 8)     = *(const float4*)(W2 + tid * 8);
    *(float4*)(w2s + tid * 8 + 4) = *(const float4*)(W2 + tid * 8 + 4);
    if (tid < 128)
      *(float4*)(w3s + tid * 4) = *(const float4*)(rW3 + c * 512 + tid * 4);
  }

  f32x4 acc[4] = {};
  const u16* xrow  = xbf + (((u32)r0 + wv * 16 + lr) << 9);
  const u16* wbase = rw1pt + ((u32)c * 64 << 9);
  for (int kb = 0; kb < 16; ++kb) {
    short8 a = *(const short8*)(xrow + kb * 32 + q * 8);
#pragma unroll
    for (int u = 0; u < 4; ++u) {
      short8 b = *(const short8*)(wbase + (((u32)(u * 16 + lr)) << 9) + kb * 32 + q * 8);
      acc[u] = __builtin_amdgcn_mfma_f32_16x16x32_bf16(a, b, acc[u], 0, 0, 0);
    }
  }
#pragma unroll
  for (int u = 0; u < 4; ++u) {
    int n = u * 16 + lr;
    float bias = rb1p[c * 64 + n];
#pragma unroll
    for (int i = 0; i < 4; ++i) {
      float v = acc[u][i] + bias;
      h1l[wv * 16 + q * 4 + i][n] = v > 0.f ? v : 0.f;
    }
  }
  __syncthreads();
  // h2: 4 threads per row, 8 cols each
  {
    int row = tid >> 2, part = (tid & 3) * 8;
    float hv[8];
#pragma unroll
    for (int j = 0; j < 8; ++j) hv[j] = rb2[c * 32 + part + j];
#pragma unroll
    for (int k = 0; k < 64; ++k) {
      float hk = h1l[row][k];
#pragma unroll
      for (int j = 0; j < 8; ++j) hv[j] += hk * w2s[k * 32 + part + j];
    }
#pragma unroll
    for (int j = 0; j < 8; ++j) h2l[row][part + j] = hv[j] > 0.f ? hv[j] : 0.f;
  }
  __syncthreads();
  // logits + softmax: 4 threads per row, 4 experts each, quad shuffle reduce
  {
    int row = tid >> 2, e0 = (tid & 3) * 4;
    float lg[4];
#pragma unroll
    for (int e = 0; e < 4; ++e) {
      float a3 = rb3[c * 16 + e0 + e];
#pragma unroll
      for (int k = 0; k < 32; ++k) a3 += h2l[row][k] * w3s[k * 16 + e0 + e];
      lg[e] = a3;
    }
    float mx = fmaxf(fmaxf(lg[0], lg[1]), fmaxf(lg[2], lg[3]));
    mx = fmaxf(mx, __shfl_xor(mx, 1, 64));
    mx = fmaxf(mx, __shfl_xor(mx, 2, 64));
    float sm = 0.f;
#pragma unroll
    for (int e = 0; e < 4; ++e) { lg[e] = __expf(lg[e] - mx); sm += lg[e]; }
    sm += __shfl_xor(sm, 1, 64);
    sm += __shfl_xor(sm, 2, 64);
    float inv = 1.f / sm;
    float4 o; o.x = lg[0] * inv; o.y = lg[1] * inv; o.z = lg[2] * inv; o.w = lg[3] * inv;
    *(float4*)(rwbuf + ((u32)c * NB + r0 + row) * 16 + e0) = o;
  }
}

// ---------------- K3: experts ----------------
// 128x128 tile, BK=32, 3 LDS buffers, depth-2 prefetch, counted vmcnt (T4),
// single raw s_barrier per K-step.
__global__ __launch_bounds__(256, 3) void k_expert(
    const u16* __restrict__ xbf, const u16* __restrict__ w1pt,
    const float* __restrict__ b1p, const u16* __restrict__ w2t,
    const float* __restrict__ eb2, const float* __restrict__ eW3,
    const float* __restrict__ eb3, float* __restrict__ sbuf)
{
  __shared__ __align__(16) unsigned char smem[49152];   // 3 x 16KB bufs
  const int tid = threadIdx.x;
  const int lane = tid & 63;
  const int wv = tid >> 6;
  const int q = lane >> 4;
  const int lr = lane & 15;
  const int pair = blockIdx.x & 31;
  const int bt = blockIdx.x >> 5;
  const int r0 = bt * 128;
  const int wr = wv >> 1, wc = wv & 1;

  f32x4 acc[4][4] = {};

  // per buf: xs[128][32]bf16 @ +0, ws[128][32]bf16 @ +8192.
  // 16B slot (row,kq) stored at slot row*4 + (kq ^ ((row>>1)&3)) (involution)
  auto stage = [&](int bufoff, int kb) {
#pragma unroll
    for (int i = 0; i < 2; ++i) {
      int s = ((wv * 2048 + i * 1024) >> 4) + lane;
      int row = s >> 2;
      int kq = (s & 3) ^ ((row >> 1) & 3);
      const u16* src = xbf + (((u32)(r0 + row)) << 9) + kb * 32 + kq * 8;
      __builtin_amdgcn_global_load_lds(AS_GLOBAL(src),
          AS_LDS(smem + bufoff + wv * 2048 + i * 1024), 16, 0, 0);
    }
#pragma unroll
    for (int i = 0; i < 2; ++i) {
      int s = ((wv * 2048 + i * 1024) >> 4) + lane;
      int n = s >> 2;
      int kq = (s & 3) ^ ((n >> 1) & 3);
      const u16* src = w1pt + (((u32)pair * 128 + n) << 9) + kb * 32 + kq * 8;
      __builtin_amdgcn_global_load_lds(AS_GLOBAL(src),
          AS_LDS(smem + bufoff + 8192 + wv * 2048 + i * 1024), 16, 0, 0);
    }
  };

  // prologue: prefetch tiles 0,1; publish tile 0
  stage(0, 0);
  stage(16384, 1);
  asm volatile("s_waitcnt vmcnt(4)" ::: "memory");   // stage(0) landed
  __builtin_amdgcn_s_barrier();

#pragma unroll
  for (int kb = 0; kb < 16; ++kb) {
    const int cur = (kb % 3) * 16384;
    short8 a[4], b[4];
#pragma unroll
    for (int t = 0; t < 4; ++t) {
      int row = wr * 64 + t * 16 + lr;
      int slot = row * 4 + (q ^ ((row >> 1) & 3));
      a[t] = *(const short8*)(smem + cur + slot * 16);
    }
#pragma unroll
    for (int u = 0; u < 4; ++u) {
      int n = wc * 64 + u * 16 + lr;
      int slot = n * 4 + (q ^ ((n >> 1) & 3));
      b[u] = *(const short8*)(smem + cur + 8192 + slot * 16);
    }
    if (kb < 14) stage(((kb + 2) % 3) * 16384, kb + 2);
    __builtin_amdgcn_sched_barrier(0);
    // my reads done (buffer (kb-1)%3 now safe to overwrite by stage(kb+2));
    // vmcnt: stage(kb+2) may stay in flight, stage(kb+1) must have landed.
    if (kb < 14) asm volatile("s_waitcnt vmcnt(4) lgkmcnt(0)" ::: "memory");
    else         asm volatile("s_waitcnt vmcnt(0) lgkmcnt(0)" ::: "memory");
    __builtin_amdgcn_s_barrier();
    __builtin_amdgcn_sched_barrier(0);
#pragma unroll
    for (int t = 0; t < 4; ++t)
#pragma unroll
      for (int u = 0; u < 4; ++u)
        acc[t][u] = __builtin_amdgcn_mfma_f32_16x16x32_bf16(a[t], b[u], acc[t][u], 0, 0, 0);
  }

  // h1 = relu(acc + b1') -> bf16 in smem[0..32K), row-major [128][128], XOR-swizzled
  {
    const float* b1 = b1p + pair * NH;
    float bias[4];
#pragma unroll
    for (int u = 0; u < 4; ++u) bias[u] = b1[wc * 64 + u * 16 + lr];
#pragma unroll
    for (int t = 0; t < 4; ++t)
#pragma unroll
      for (int u = 0; u < 4; ++u) {
        int n = wc * 64 + u * 16 + lr;
#pragma unroll
        for (int i = 0; i < 4; ++i) {
          int row = wr * 64 + t * 16 + q * 4 + i;
          float v = acc[t][u][i] + bias[u];
          v = v > 0.f ? v : 0.f;
          int byteoff = (row * 256 + n * 2) ^ ((row & 7) << 4);
          *(u16*)(smem + byteoff) = f2bf(v);
        }
      }
  }
  __syncthreads();

  // GEMM2: h2[128x64] = h1[128x128] @ W2T; wave wv owns rows wv*32..+31
  f32x4 acc2[2][4] = {};
  const u16* w2 = w2t + (u32)pair * 64 * NH;
#pragma unroll
  for (int kb2 = 0; kb2 < 4; ++kb2) {
    short8 a2[2], bb[4];
#pragma unroll
    for (int t2 = 0; t2 < 2; ++t2) {
      int row = wv * 32 + t2 * 16 + lr;
      int byteoff = (row * 256 + kb2 * 64 + q * 16) ^ ((row & 7) << 4);
      a2[t2] = *(const short8*)(smem + byteoff);
    }
#pragma unroll
    for (int u2 = 0; u2 < 4; ++u2) {
      int n = u2 * 16 + lr;
      bb[u2] = *(const short8*)(w2 + n * NH + kb2 * 32 + q * 8);
    }
#pragma unroll
    for (int t2 = 0; t2 < 2; ++t2)
#pragma unroll
      for (int u2 = 0; u2 < 4; ++u2)
        acc2[t2][u2] = __builtin_amdgcn_mfma_f32_16x16x32_bf16(a2[t2], bb[u2], acc2[t2][u2], 0, 0, 0);
  }

  // epilogue: s = sigmoid(relu(h2 + b2) . W3 + b3)
  {
    const float* b2 = eb2 + pair * 64;
    const float* w3 = eW3 + pair * 64;
    float b3 = eb3[pair];
    float bb2[4], bw3[4];
#pragma unroll
    for (int u2 = 0; u2 < 4; ++u2) {
      int n = u2 * 16 + lr;
      bb2[u2] = b2[n];
      bw3[u2] = w3[n];
    }
#pragma unroll
    for (int t2 = 0; t2 < 2; ++t2) {
      float p[4] = {0.f, 0.f, 0.f, 0.f};
#pragma unroll
      for (int u2 = 0; u2 < 4; ++u2)
#pragma unroll
        for (int i = 0; i < 4; ++i) {
          float h = acc2[t2][u2][i] + bb2[u2];
          h = h > 0.f ? h : 0.f;
          p[i] += h * bw3[u2];
        }
#pragma unroll
      for (int m = 1; m < 16; m <<= 1)
#pragma unroll
        for (int i = 0; i < 4; ++i) p[i] += __shfl_xor(p[i], m, 64);
      if (lr == 0) {
#pragma unroll
        for (int i = 0; i < 4; ++i) {
          int row = wv * 32 + t2 * 16 + q * 4 + i;
          float z = p[i] + b3;
          sbuf[(u32)pair * NB + r0 + row] = 1.f / (1.f + __expf(-z));
        }
      }
    }
  }
}

// ---------------- K4: combine ----------------
__global__ void k_combine(const float* __restrict__ rwbuf, const float* __restrict__ sbuf,
                          const float* __restrict__ bw, float* __restrict__ out)
{
  int b = blockIdx.x * 256 + threadIdx.x;
  float total = 0.f;
#pragma unroll
  for (int c = 0; c < 2; ++c) {
    const float* rwp = rwbuf + ((u32)c * NB + b) * 16;
    float acc = 0.f;
#pragma unroll
    for (int e = 0; e < 16; ++e)
      acc += rwp[e] * sbuf[((u32)(c * 16 + e)) * NB + b];
    total += bw[c] * acc;
  }
  out[b] = total;
}

extern "C" void kernel_launch(void* const* d_in, const int* in_sizes, int n_in,
                              void* d_out, int out_size, void* d_ws, size_t ws_size,
                              hipStream_t stream) {
  const float* x     = (const float*)d_in[0];
  const float* rbn_g = (const float*)d_in[1];
  const float* rbn_b = (const float*)d_in[2];
  const float* rbn_m = (const float*)d_in[3];
  const float* rbn_v = (const float*)d_in[4];
  const float* rW1   = (const float*)d_in[5];
  const float* rb1   = (const float*)d_in[6];
  const float* rW2   = (const float*)d_in[7];
  const float* rb2   = (const float*)d_in[8];
  const float* rW3   = (const float*)d_in[9];
  const float* rb3   = (const float*)d_in[10];
  const float* ebn_g = (const float*)d_in[11];
  const float* ebn_b = (const float*)d_in[12];
  const float* ebn_m = (const float*)d_in[13];
  const float* ebn_v = (const float*)d_in[14];
  const float* eW1   = (const float*)d_in[15];
  const float* eb1   = (const float*)d_in[16];
  const float* eW2   = (const float*)d_in[17];
  const float* eb2   = (const float*)d_in[18];
  const float* eW3   = (const float*)d_in[19];
  const float* eb3   = (const float*)d_in[20];
  const float* bw    = (const float*)d_in[21];

  char* ws = (char*)d_ws;
  u16*   xbf   = (u16*)(ws + OFF_XBF);
  u16*   w1pt  = (u16*)(ws + OFF_W1PT);
  u16*   w2t   = (u16*)(ws + OFF_W2T);
  u16*   rw1pt = (u16*)(ws + OFF_RW1PT);
  float* b1p   = (float*)(ws + OFF_B1P);
  float* rb1p  = (float*)(ws + OFF_RB1P);
  float* rwbuf = (float*)(ws + OFF_RW);
  float* sbuf  = (float*)(ws + OFF_S);
  float* pbias = (float*)(ws + OFF_RW);   // alias: dead before k_router writes rwbuf

  k_cvt_x<<<dim3(NB * ND / 8 / 256), dim3(256), 0, stream>>>(x, xbf);
  k_prep_w1<<<dim3(256), dim3(256), 0, stream>>>(
      ebn_g, ebn_b, ebn_m, ebn_v, eW1, w1pt, pbias);
  k_prep_rest<<<dim3(34), dim3(256), 0, stream>>>(
      pbias, eb1, eW2, rbn_g, rbn_b, rbn_m, rbn_v, rW1, rb1,
      b1p, w2t, rw1pt, rb1p);
  k_router<<<dim3(256), dim3(256), 0, stream>>>(
      xbf, rw1pt, rb1p, rW2, rb2, rW3, rb3, rwbuf);
  k_expert<<<dim3(2048), dim3(256), 0, stream>>>(
      xbf, w1pt, b1p, w2t, eb2, eW3, eb3, sbuf);
  k_combine<<<dim3(NB / 256), dim3(256), 0, stream>>>(rwbuf, sbuf, bw, (float*)d_out);
}

// Round 3
// 100.624 us; speedup vs baseline: 1.2967x; 1.0321x over previous
//
#include <hip/hip_runtime.h>

typedef __attribute__((ext_vector_type(8))) short short8;
typedef __attribute__((ext_vector_type(8))) unsigned short ushort8;
typedef __attribute__((ext_vector_type(4))) float f32x4;
typedef unsigned int u32;
typedef unsigned short u16;

#define AS_GLOBAL(p) ((const __attribute__((address_space(1))) u32*)(p))
#define AS_LDS(p) ((__attribute__((address_space(3))) u32*)(p))

#define NB 8192
#define ND 512
#define NH 128

// workspace byte offsets
#define OFF_XBF    0u          // [8192][512] bf16
#define OFF_W1PT   8388608u    // [32][128][512] bf16  (W1' transposed, BN folded)
#define OFF_W2T    12582912u   // [32][64][128] bf16   (eW2 transposed)
#define OFF_RW1PT  13107200u   // [2][64][512] bf16
#define OFF_B1P    13238272u   // [32][128] f32
#define OFF_RB1P   13254656u   // [2][64] f32
#define OFF_RWT    13255168u   // [32][8192] f32  router weights TRANSPOSED [pair][b]
#define OFF_PBIAS  14303744u   // [32][8][128] f32 partial bias (old sbuf region)

__device__ __forceinline__ u16 f2bf(float f) {
  union { float f; u32 u; } v; v.f = f;
  return (u16)((v.u + 0x7FFFu + ((v.u >> 16) & 1u)) >> 16);
}

// ================= K_A: fused prep =================
// blocks: [0,2048) cvt_x | [2048,2304) fold W1 | [2304,2336) W2^T
//         [2336,2338) router fold | 2338 zero d_out
__global__ __launch_bounds__(256) void k_prep_all(
    const float* __restrict__ x, u16* __restrict__ xbf,
    const float* __restrict__ eg, const float* __restrict__ ebb,
    const float* __restrict__ em, const float* __restrict__ ev,
    const float* __restrict__ eW1, u16* __restrict__ w1pt, float* __restrict__ pbias,
    const float* __restrict__ eW2, u16* __restrict__ w2t,
    const float* __restrict__ rbn_g, const float* __restrict__ rbn_b,
    const float* __restrict__ rbn_m, const float* __restrict__ rbn_v,
    const float* __restrict__ rW1, const float* __restrict__ rb1,
    u16* __restrict__ rw1pt, float* __restrict__ rb1p,
    float* __restrict__ out)
{
  __shared__ __align__(16) unsigned char sh[17920];
  const int blk = blockIdx.x, t = threadIdx.x;
  if (blk < 2048) {
    int i = (blk * 256 + t) * 8;
    const float4* p = (const float4*)(x + i);
    float4 v0 = p[0], v1 = p[1];
    ushort8 r;
    r[0] = f2bf(v0.x); r[1] = f2bf(v0.y); r[2] = f2bf(v0.z); r[3] = f2bf(v0.w);
    r[4] = f2bf(v1.x); r[5] = f2bf(v1.y); r[6] = f2bf(v1.z); r[7] = f2bf(v1.w);
    *(ushort8*)(xbf + i) = r;
  } else if (blk < 2304) {
    float* sa = (float*)sh;                 // [64]
    float* sc = sa + 64;                    // [64]
    u16* tile = (u16*)(sc + 64);            // [64][128]
    float* pb2 = (float*)(tile + 64 * 128); // [2][128]
    const int pair = (blk - 2048) >> 3, dc = (blk - 2048) & 7;
    const int d0 = dc * 64;
    if (t < 64) {
      int d = pair * ND + d0 + t;
      float a = eg[d] * rsqrtf(ev[d] + 1e-5f);
      sa[t] = a;
      sc[t] = ebb[d] - em[d] * a;
    }
    __syncthreads();
    const int h = t & 127, pr = t >> 7;
    float acc = 0.f;
    const float* src = eW1 + (size_t)pair * ND * NH + (size_t)d0 * NH;
#pragma unroll
    for (int i = 0; i < 32; ++i) {
      int dl = i * 2 + pr;
      float w = src[dl * NH + h];
      tile[dl * 128 + h] = f2bf(w * sa[dl]);
      acc += w * sc[dl];
    }
    pb2[pr * 128 + h] = acc;
    __syncthreads();
    {
      int hh = t >> 1, half = t & 1;
      u16* dst = w1pt + ((u32)(pair * NH + hh)) * ND + d0 + half * 32;
#pragma unroll
      for (int v8 = 0; v8 < 4; ++v8) {
        ushort8 r;
#pragma unroll
        for (int j = 0; j < 8; ++j) r[j] = tile[(half * 32 + v8 * 8 + j) * 128 + hh];
        *(ushort8*)(dst + v8 * 8) = r;
      }
    }
    if (t < 128) pbias[(u32)(pair * 8 + dc) * 128 + t] = pb2[t] + pb2[128 + t];
  } else if (blk < 2336) {
    const int pair = blk - 2304;
    const float* w2 = eW2 + (size_t)pair * NH * 64;
    int n = t & 63, kk = t >> 6;
    for (int k = kk * 32; k < kk * 32 + 32; ++k)
      w2t[((u32)pair * 64 + n) * NH + k] = f2bf(w2[k * 64 + n]);
  } else if (blk < 2338) {
    const int c = blk - 2336;
    int n = t >> 2, q = t & 3;
    const float* g  = rbn_g + c * ND;
    const float* b  = rbn_b + c * ND;
    const float* m  = rbn_m + c * ND;
    const float* vv = rbn_v + c * ND;
    const float* w1 = rW1 + (size_t)c * ND * 64;
    float acc = 0.f;
    for (int d = q * 128; d < q * 128 + 128; ++d) {
      float a  = g[d] * rsqrtf(vv[d] + 1e-5f);
      float cc = b[d] - m[d] * a;
      float w  = w1[d * 64 + n];
      rw1pt[((u32)c * 64 + n) * ND + d] = f2bf(a * w);
      acc += cc * w;
    }
    acc += __shfl_xor(acc, 1, 64);
    acc += __shfl_xor(acc, 2, 64);
    if (q == 0) rb1p[c * 64 + n] = rb1[c * 64 + n] + acc;
  } else {
    float4 z; z.x = 0.f; z.y = 0.f; z.z = 0.f; z.w = 0.f;
    float4* o4 = (float4*)out;
#pragma unroll
    for (int j = 0; j < 8; ++j) o4[t * 8 + j] = z;
  }
}

// ================= K_R: router (blocks 0..255) + bias reduce (256..287) =================
__global__ __launch_bounds__(256) void k_router(
    const u16* __restrict__ xbf, const u16* __restrict__ rw1pt,
    const float* __restrict__ rb1p, const float* __restrict__ rW2,
    const float* __restrict__ rb2, const float* __restrict__ rW3,
    const float* __restrict__ rb3, float* __restrict__ rwT,
    const float* __restrict__ pbias, const float* __restrict__ eb1,
    float* __restrict__ b1p)
{
  __shared__ float h1l[64][65];
  __shared__ float h2l[64][33];
  __shared__ float w2s[2048];
  __shared__ float w3s[512];
  const int tid = threadIdx.x;
  if (blockIdx.x >= 256) {
    const int pair = blockIdx.x - 256;
    if (tid < 128) {
      float s = eb1[pair * NH + tid];
#pragma unroll
      for (int dc = 0; dc < 8; ++dc) s += pbias[(u32)(pair * 8 + dc) * 128 + tid];
      b1p[pair * NH + tid] = s;
    }
    return;
  }
  const int lane = tid & 63;
  const int wv = tid >> 6;
  const int q = lane >> 4;
  const int lr = lane & 15;
  const int c = blockIdx.x >> 7;
  const int r0 = (blockIdx.x & 127) * 64;

  {
    const float* W2 = rW2 + c * 2048;
    *(float4*)(w2s + tid * 8)     = *(const float4*)(W2 + tid * 8);
    *(float4*)(w2s + tid * 8 + 4) = *(const float4*)(W2 + tid * 8 + 4);
    if (tid < 128)
      *(float4*)(w3s + tid * 4) = *(const float4*)(rW3 + c * 512 + tid * 4);
  }

  f32x4 acc[4] = {};
  const u16* xrow  = xbf + (((u32)r0 + wv * 16 + lr) << 9);
  const u16* wbase = rw1pt + ((u32)c * 64 << 9);
  for (int kb = 0; kb < 16; ++kb) {
    short8 a = *(const short8*)(xrow + kb * 32 + q * 8);
#pragma unroll
    for (int u = 0; u < 4; ++u) {
      short8 b = *(const short8*)(wbase + (((u32)(u * 16 + lr)) << 9) + kb * 32 + q * 8);
      acc[u] = __builtin_amdgcn_mfma_f32_16x16x32_bf16(a, b, acc[u], 0, 0, 0);
    }
  }
#pragma unroll
  for (int u = 0; u < 4; ++u) {
    int n = u * 16 + lr;
    float bias = rb1p[c * 64 + n];
#pragma unroll
    for (int i = 0; i < 4; ++i) {
      float v = acc[u][i] + bias;
      h1l[wv * 16 + q * 4 + i][n] = v > 0.f ? v : 0.f;
    }
  }
  __syncthreads();
  {
    int row = tid >> 2, part = (tid & 3) * 8;
    float hv[8];
#pragma unroll
    for (int j = 0; j < 8; ++j) hv[j] = rb2[c * 32 + part + j];
#pragma unroll
    for (int k = 0; k < 64; ++k) {
      float hk = h1l[row][k];
#pragma unroll
      for (int j = 0; j < 8; ++j) hv[j] += hk * w2s[k * 32 + part + j];
    }
#pragma unroll
    for (int j = 0; j < 8; ++j) h2l[row][part + j] = hv[j] > 0.f ? hv[j] : 0.f;
  }
  __syncthreads();
  {
    int row = tid >> 2, e0 = (tid & 3) * 4;
    float lg[4];
#pragma unroll
    for (int e = 0; e < 4; ++e) {
      float a3 = rb3[c * 16 + e0 + e];
#pragma unroll
      for (int k = 0; k < 32; ++k) a3 += h2l[row][k] * w3s[k * 16 + e0 + e];
      lg[e] = a3;
    }
    float mx = fmaxf(fmaxf(lg[0], lg[1]), fmaxf(lg[2], lg[3]));
    mx = fmaxf(mx, __shfl_xor(mx, 1, 64));
    mx = fmaxf(mx, __shfl_xor(mx, 2, 64));
    float sm = 0.f;
#pragma unroll
    for (int e = 0; e < 4; ++e) { lg[e] = __expf(lg[e] - mx); sm += lg[e]; }
    sm += __shfl_xor(sm, 1, 64);
    sm += __shfl_xor(sm, 2, 64);
    float inv = 1.f / sm;
#pragma unroll
    for (int e = 0; e < 4; ++e)
      rwT[(u32)(c * 16 + e0 + e) * NB + r0 + row] = lg[e] * inv;
  }
}

// ================= K_E: experts =================
// 128x128 tile, BK=32, 2 LDS bufs (32KB), 2-phase schedule, address math hoisted.
__global__ __launch_bounds__(256, 4) void k_expert(
    const u16* __restrict__ xbf, const u16* __restrict__ w1pt,
    const float* __restrict__ b1p, const u16* __restrict__ w2t,
    const float* __restrict__ eb2, const float* __restrict__ eW3,
    const float* __restrict__ eb3, const float* __restrict__ rwT,
    const float* __restrict__ bw, float* __restrict__ out)
{
  __shared__ __align__(16) unsigned char smem[32768];
  const int tid = threadIdx.x;
  const int lane = tid & 63;
  const int wv = tid >> 6;
  const int q = lane >> 4;
  const int lr = lane & 15;
  const int pair = blockIdx.x & 31;
  const int bt = blockIdx.x >> 5;
  const int r0 = bt * 128;
  const int wr = wv >> 1, wc = wv & 1;

  // precomputed swizzled ds_read byte offsets (within a buf)
  int offA[4], offB[4];
#pragma unroll
  for (int t = 0; t < 4; ++t) {
    int row = wr * 64 + t * 16 + lr;
    offA[t] = (row * 4 + (q ^ ((row >> 1) & 3))) * 16;
    int n = wc * 64 + t * 16 + lr;
    offB[t] = 8192 + (n * 4 + (q ^ ((n >> 1) & 3))) * 16;
  }
  // staging source pointers (advance 32 bf16 = 64B per K-step)
  const int s0 = wv * 128 + lane, s1 = s0 + 64;
  const int rx0 = s0 >> 2, kq0 = (s0 & 3) ^ ((rx0 >> 1) & 3);
  const int rx1 = s1 >> 2, kq1 = (s1 & 3) ^ ((rx1 >> 1) & 3);
  const u16* px0 = xbf + (((u32)(r0 + rx0)) << 9) + kq0 * 8;
  const u16* px1 = xbf + (((u32)(r0 + rx1)) << 9) + kq1 * 8;
  const u16* pw0 = w1pt + (((u32)(pair * 128 + rx0)) << 9) + kq0 * 8;
  const u16* pw1 = w1pt + (((u32)(pair * 128 + rx1)) << 9) + kq1 * 8;
  const u32 ld0 = (u32)wv * 2048, ld1 = (u32)wv * 2048 + 1024;

  f32x4 acc[4][4] = {};

#define STAGE(BUFOFF) do { \
  __builtin_amdgcn_global_load_lds(AS_GLOBAL(px0), AS_LDS(smem + (BUFOFF) + ld0), 16, 0, 0); \
  __builtin_amdgcn_global_load_lds(AS_GLOBAL(px1), AS_LDS(smem + (BUFOFF) + ld1), 16, 0, 0); \
  __builtin_amdgcn_global_load_lds(AS_GLOBAL(pw0), AS_LDS(smem + (BUFOFF) + 8192 + ld0), 16, 0, 0); \
  __builtin_amdgcn_global_load_lds(AS_GLOBAL(pw1), AS_LDS(smem + (BUFOFF) + 8192 + ld1), 16, 0, 0); \
  px0 += 32; px1 += 32; pw0 += 32; pw1 += 32; } while (0)

#define KSTEP(CUR, NXT, DO_STAGE) do { \
  if (DO_STAGE) STAGE(NXT); \
  short8 a_[4], b_[4]; \
  _Pragma("unroll") for (int t = 0; t < 4; ++t) a_[t] = *(const short8*)(smem + (CUR) + offA[t]); \
  _Pragma("unroll") for (int u = 0; u < 4; ++u) b_[u] = *(const short8*)(smem + (CUR) + offB[u]); \
  asm volatile("s_waitcnt lgkmcnt(0)" ::: "memory"); \
  __builtin_amdgcn_sched_barrier(0); \
  _Pragma("unroll") for (int t = 0; t < 4; ++t) \
    _Pragma("unroll") for (int u = 0; u < 4; ++u) \
      acc[t][u] = __builtin_amdgcn_mfma_f32_16x16x32_bf16(a_[t], b_[u], acc[t][u], 0, 0, 0); \
  __builtin_amdgcn_sched_barrier(0); \
  if (DO_STAGE) asm volatile("s_waitcnt vmcnt(0)" ::: "memory"); \
  __builtin_amdgcn_s_barrier(); } while (0)

  STAGE(0);
  asm volatile("s_waitcnt vmcnt(0)" ::: "memory");
  __builtin_amdgcn_s_barrier();
#pragma unroll
  for (int kk = 0; kk < 8; ++kk) {
    KSTEP(0, 16384, true);
    KSTEP(16384, 0, (kk < 7));
  }
#undef KSTEP
#undef STAGE

  // h1 = relu(acc + b1') -> bf16, [128][128] XOR-swizzled over full 32KB
  {
    const float* b1 = b1p + pair * NH;
    float bias[4];
#pragma unroll
    for (int u = 0; u < 4; ++u) bias[u] = b1[wc * 64 + u * 16 + lr];
#pragma unroll
    for (int t = 0; t < 4; ++t)
#pragma unroll
      for (int u = 0; u < 4; ++u) {
        int n = wc * 64 + u * 16 + lr;
#pragma unroll
        for (int i = 0; i < 4; ++i) {
          int row = wr * 64 + t * 16 + q * 4 + i;
          float v = acc[t][u][i] + bias[u];
          v = v > 0.f ? v : 0.f;
          int byteoff = (row * 256 + n * 2) ^ ((row & 7) << 4);
          *(u16*)(smem + byteoff) = f2bf(v);
        }
      }
  }
  __syncthreads();

  // GEMM2: h2[128x64] = h1 @ W2T; wave owns rows wv*32..+31
  f32x4 acc2[2][4] = {};
  const u16* w2 = w2t + (u32)pair * 64 * NH;
#pragma unroll
  for (int kb2 = 0; kb2 < 4; ++kb2) {
    short8 a2[2], bb[4];
#pragma unroll
    for (int t2 = 0; t2 < 2; ++t2) {
      int row = wv * 32 + t2 * 16 + lr;
      int byteoff = (row * 256 + kb2 * 64 + q * 16) ^ ((row & 7) << 4);
      a2[t2] = *(const short8*)(smem + byteoff);
    }
#pragma unroll
    for (int u2 = 0; u2 < 4; ++u2) {
      int n = u2 * 16 + lr;
      bb[u2] = *(const short8*)(w2 + n * NH + kb2 * 32 + q * 8);
    }
#pragma unroll
    for (int t2 = 0; t2 < 2; ++t2)
#pragma unroll
      for (int u2 = 0; u2 < 4; ++u2)
        acc2[t2][u2] = __builtin_amdgcn_mfma_f32_16x16x32_bf16(a2[t2], bb[u2], acc2[t2][u2], 0, 0, 0);
  }

  // epilogue: s = sigmoid(relu(h2+b2).W3 + b3); out += bw_c * rw * s  (atomic)
  {
    const float* b2 = eb2 + pair * 64;
    const float* w3 = eW3 + pair * 64;
    float b3 = eb3[pair];
    float bwc = bw[pair >> 4];
    float bb2[4], bw3[4];
#pragma unroll
    for (int u2 = 0; u2 < 4; ++u2) {
      int n = u2 * 16 + lr;
      bb2[u2] = b2[n];
      bw3[u2] = w3[n];
    }
#pragma unroll
    for (int t2 = 0; t2 < 2; ++t2) {
      float p[4] = {0.f, 0.f, 0.f, 0.f};
#pragma unroll
      for (int u2 = 0; u2 < 4; ++u2)
#pragma unroll
        for (int i = 0; i < 4; ++i) {
          float h = acc2[t2][u2][i] + bb2[u2];
          h = h > 0.f ? h : 0.f;
          p[i] += h * bw3[u2];
        }
#pragma unroll
      for (int m = 1; m < 16; m <<= 1)
#pragma unroll
        for (int i = 0; i < 4; ++i) p[i] += __shfl_xor(p[i], m, 64);
      if (lr == 0) {
#pragma unroll
        for (int i = 0; i < 4; ++i) {
          int row = wv * 32 + t2 * 16 + q * 4 + i;
          float z = p[i] + b3;
          float s = 1.f / (1.f + __expf(-z));
          float rw = rwT[(u32)pair * NB + r0 + row];
          atomicAdd(out + r0 + row, bwc * rw * s);
        }
      }
    }
  }
}

extern "C" void kernel_launch(void* const* d_in, const int* in_sizes, int n_in,
                              void* d_out, int out_size, void* d_ws, size_t ws_size,
                              hipStream_t stream) {
  const float* x     = (const float*)d_in[0];
  const float* rbn_g = (const float*)d_in[1];
  const float* rbn_b = (const float*)d_in[2];
  const float* rbn_m = (const float*)d_in[3];
  const float* rbn_v = (const float*)d_in[4];
  const float* rW1   = (const float*)d_in[5];
  const float* rb1   = (const float*)d_in[6];
  const float* rW2   = (const float*)d_in[7];
  const float* rb2   = (const float*)d_in[8];
  const float* rW3   = (const float*)d_in[9];
  const float* rb3   = (const float*)d_in[10];
  const float* ebn_g = (const float*)d_in[11];
  const float* ebn_b = (const float*)d_in[12];
  const float* ebn_m = (const float*)d_in[13];
  const float* ebn_v = (const float*)d_in[14];
  const float* eW1   = (const float*)d_in[15];
  const float* eb1   = (const float*)d_in[16];
  const float* eW2   = (const float*)d_in[17];
  const float* eb2   = (const float*)d_in[18];
  const float* eW3   = (const float*)d_in[19];
  const float* eb3   = (const float*)d_in[20];
  const float* bw    = (const float*)d_in[21];

  char* ws = (char*)d_ws;
  u16*   xbf   = (u16*)(ws + OFF_XBF);
  u16*   w1pt  = (u16*)(ws + OFF_W1PT);
  u16*   w2t   = (u16*)(ws + OFF_W2T);
  u16*   rw1pt = (u16*)(ws + OFF_RW1PT);
  float* b1p   = (float*)(ws + OFF_B1P);
  float* rb1p  = (float*)(ws + OFF_RB1P);
  float* rwT   = (float*)(ws + OFF_RWT);
  float* pbias = (float*)(ws + OFF_PBIAS);
  float* outf  = (float*)d_out;

  k_prep_all<<<dim3(2339), dim3(256), 0, stream>>>(
      x, xbf, ebn_g, ebn_b, ebn_m, ebn_v, eW1, w1pt, pbias, eW2, w2t,
      rbn_g, rbn_b, rbn_m, rbn_v, rW1, rb1, rw1pt, rb1p, outf);
  k_router<<<dim3(288), dim3(256), 0, stream>>>(
      xbf, rw1pt, rb1p, rW2, rb2, rW3, rb3, rwT, pbias, eb1, b1p);
  k_expert<<<dim3(2048), dim3(256), 0, stream>>>(
      xbf, w1pt, b1p, w2t, eb2, eW3, eb3, rwT, bw, outf);
}